// Round 9
// baseline (134.293 us; speedup 1.0000x reference)
//
#include <hip/hip_runtime.h>
#include <hip/hip_bf16.h>

typedef __attribute__((ext_vector_type(8))) short short8;
typedef __attribute__((ext_vector_type(8))) unsigned short u16x8;
typedef __attribute__((ext_vector_type(4))) unsigned short u16x4;
typedef __attribute__((ext_vector_type(4))) float f32x4;
typedef __attribute__((ext_vector_type(16))) float f32x16;
typedef __attribute__((ext_vector_type(4))) int int4v;

#define S_  2048
#define D_  1024
#define F3  3072
#define QKLD 2048                  // qk buffer: row s -> [h][q 64 | k 64]
#define LOG2E 1.4426950408889634f
#define C_SCALE (0.125f * LOG2E)   // 1/sqrt(64) folded into exp2

__device__ __forceinline__ unsigned short f2bf(float f) {
  unsigned int u = __builtin_bit_cast(unsigned int, f);
  u += 0x7fffu + ((u >> 16) & 1u);
  return (unsigned short)(u >> 16);
}
__device__ __forceinline__ float fast_exp2(float x) {
  float r;
  asm("v_exp_f32 %0, %1" : "=v"(r) : "v"(x));
  return r;
}
__device__ __forceinline__ int cvtpk_bf16(float lo, float hi) {
  int r;
  asm("v_cvt_pk_bf16_f32 %0, %1, %2" : "=v"(r) : "v"(lo), "v"(hi));
  return r;
}
// C-layout (32x32, regs p0..p7 = half) -> MFMA B-operand frag, in-register (VERIFIED R8)
__device__ __forceinline__ short8 mkfrag(float p0, float p1, float p2, float p3,
                                         float p4, float p5, float p6, float p7) {
  int wA = cvtpk_bf16(p0, p1);
  int wB = cvtpk_bf16(p2, p3);
  int wC = cvtpk_bf16(p4, p5);
  int wD = cvtpk_bf16(p6, p7);
  asm volatile("v_permlane32_swap_b32 %0, %1" : "+v"(wA), "+v"(wC));
  asm volatile("v_permlane32_swap_b32 %0, %1" : "+v"(wB), "+v"(wD));
  int4v f = {wA, wB, wC, wD};
  return __builtin_bit_cast(short8, f);
}

// XOR swizzle for 128B LDS rows (8 x 16B chunks), 3-bit key
__device__ __forceinline__ int swz(int row, int col) {    // -> BYTE offset
  int byte = (row << 7) + (col << 1);
  return byte ^ ((((row & 7) ^ ((row >> 3) & 7)) << 4));
}
__device__ __forceinline__ unsigned short* ldsp(unsigned short* base, int byteoff) {
  return (unsigned short*)((char*)base + byteoff);
}

// ---------------- x (f32) -> bf16 ----------------
__global__ __launch_bounds__(256) void conv_x_kernel(const float* __restrict__ x,
                                                     unsigned short* __restrict__ xb) {
  int i = (blockIdx.x * 256 + threadIdx.x) * 4;
  f32x4 v = *reinterpret_cast<const f32x4*>(&x[i]);
  u16x4 o;
  o[0] = f2bf(v[0]); o[1] = f2bf(v[1]); o[2] = f2bf(v[2]); o[3] = f2bf(v[3]);
  *reinterpret_cast<u16x4*>(&xb[i]) = o;
}

// ---------------- W [1024][3072] f32 -> Wt [3072][1024] bf16 ----------------
__global__ __launch_bounds__(256) void transpose_w_kernel(const float* __restrict__ W,
                                                          unsigned short* __restrict__ Wt) {
  __shared__ float tile[64][65];
  int nt = blockIdx.x;
  int kt = blockIdx.y;
  int tid = threadIdx.x;
#pragma unroll
  for (int i = 0; i < 16; i++) {
    int idx = tid + i * 256;
    int r = idx >> 6, c = idx & 63;
    tile[r][c] = W[(size_t)(kt * 64 + r) * F3 + nt * 64 + c];
  }
  __syncthreads();
#pragma unroll
  for (int i = 0; i < 16; i++) {
    int idx = tid + i * 256;
    int rn = idx >> 6, ck = idx & 63;
    Wt[(size_t)(nt * 64 + rn) * D_ + kt * 64 + ck] = f2bf(tile[ck][rn]);
  }
}

// ------- GEMM: BK=64, gload_lds staging + 128B-row XOR swizzle, split epilogue ------
__global__ __launch_bounds__(256) void qkv_gemm_kernel(const unsigned short* __restrict__ A,
                                                       const unsigned short* __restrict__ Bt,
                                                       const float* __restrict__ bias,
                                                       unsigned short* __restrict__ qk,
                                                       unsigned short* __restrict__ vT) {
  constexpr int K = D_;
  __shared__ unsigned short sA[128 * 64];    // 16 KB, rows 128B, swizzled
  __shared__ unsigned short sB[128 * 64];
  int bn = blockIdx.x, bm = blockIdx.y;
  int tid = threadIdx.x;
  int wid = tid >> 6, lane = tid & 63;
  int wr = wid >> 1, wc = wid & 1;
  int lh = lane >> 4, l15 = lane & 15;
  f32x4 acc[4][4] = {};

  const int r0 = tid >> 3;                   // 0..31
  const int m0 = tid & 7;
  const unsigned short* gAi[4];
  const unsigned short* gBi[4];
#pragma unroll
  for (int i = 0; i < 4; i++) {
    int row = r0 + 32 * i;
    int key = (row ^ (row >> 3)) & 7;
    int col = (m0 ^ key) * 8;
    gAi[i] = &A[(size_t)(bm * 128 + row) * K + col];
    gBi[i] = &Bt[(size_t)(bn * 128 + row) * K + col];
  }

  for (int k0 = 0; k0 < K; k0 += 64) {
#pragma unroll
    for (int i = 0; i < 4; i++)
      __builtin_amdgcn_global_load_lds((const unsigned int*)(gAi[i] + k0),
                                       (unsigned int*)(&sA[i * 2048 + wid * 512]), 16, 0, 0);
#pragma unroll
    for (int i = 0; i < 4; i++)
      __builtin_amdgcn_global_load_lds((const unsigned int*)(gBi[i] + k0),
                                       (unsigned int*)(&sB[i * 2048 + wid * 512]), 16, 0, 0);
    asm volatile("s_waitcnt vmcnt(0)" ::: "memory");
    __syncthreads();

#pragma unroll
    for (int ksub = 0; ksub < 2; ksub++) {
      short8 af[4], bf[4];
#pragma unroll
      for (int m = 0; m < 4; m++) {
        int ar = wr * 64 + m * 16 + l15;
        int ab = (ar << 7) + ((((ksub << 2) | lh) ^ ((ar ^ (ar >> 3)) & 7)) << 4);
        af[m] = *reinterpret_cast<const short8*>((const char*)sA + ab);
      }
#pragma unroll
      for (int n = 0; n < 4; n++) {
        int br = wc * 64 + n * 16 + l15;
        int bb = (br << 7) + ((((ksub << 2) | lh) ^ ((br ^ (br >> 3)) & 7)) << 4);
        bf[n] = *reinterpret_cast<const short8*>((const char*)sB + bb);
      }
#pragma unroll
      for (int m = 0; m < 4; m++)
#pragma unroll
        for (int n = 0; n < 4; n++)
          acc[m][n] = __builtin_amdgcn_mfma_f32_16x16x32_bf16(af[m], bf[n], acc[m][n], 0, 0, 0);
    }
    __syncthreads();
  }

  int row0 = bm * 128 + wr * 64;
  int col0 = bn * 128 + wc * 64;
  const int bn3 = bn % 3;
  const int vside = (bn3 == 1) ? 0 : (bn3 == 2) ? 1 : -1;

  if (wc == vside) {
    unsigned short* tile = wr ? sB : sA;          // 8KB = [64 d][64 s], swizzled rows
    const int h = col0 / 192;
#pragma unroll
    for (int n = 0; n < 4; n++) {
      int d = n * 16 + l15;
      float bv = bias[col0 + n * 16 + l15];
#pragma unroll
      for (int m = 0; m < 4; m++) {
        u16x4 pk;
#pragma unroll
        for (int r = 0; r < 4; r++) pk[r] = f2bf(acc[m][n][r] + bv);
        *reinterpret_cast<u16x4*>(ldsp(tile, swz(d, m * 16 + lh * 4))) = pk;
      }
    }
    const int bbat = row0 >> 11, s0g = row0 & 2047;
    unsigned short* vrow = &vT[(size_t)(bbat * 16 + h) * 64 * S_ + s0g];
#pragma unroll
    for (int i = 0; i < 8; i++) {
      int c = lane + i * 64;
      int rrow = c >> 3, blk = c & 7;
      short8 v = *reinterpret_cast<const short8*>(ldsp(tile, swz(rrow, blk * 8)));
      *reinterpret_cast<short8*>(&vrow[(size_t)rrow * S_ + blk * 8]) = v;
    }
  } else {
#pragma unroll
    for (int n = 0; n < 4; n++) {
      int g = col0 + n * 16;
      int h = g / 192;
      int w = g % 192;
      float bv = bias[g + l15];
      int colq = h * 128 + w + l15;
#pragma unroll
      for (int m = 0; m < 4; m++)
#pragma unroll
        for (int r = 0; r < 4; r++) {
          int row = row0 + m * 16 + lh * 4 + r;
          qk[(size_t)row * QKLD + colq] = f2bf(acc[m][n][r] + bv);
        }
    }
  }
}

// -------- causal flash attention: 4 waves = (q-half i) x (k-parity j), k-split -------
// Block = (bh, 64-row strip qt). Wave (i,j) computes q-half i over k-tiles j, j+2, ...
// -> per-wave iters = ceil(T/2) <= 16 (halves the serial tail). Parity j waves always
// read buffer j. Superstep stages 2 tiles (issue-early / write-late). End: parity-1
// waves deposit (m,l,O) in LDS; parity-0 waves merge (online-softmax combine) + store.
__global__ __launch_bounds__(256, 4) void attn_kernel(const unsigned short* __restrict__ qk,
                                                      const unsigned short* __restrict__ vT,
                                                      float* __restrict__ out) {
  __shared__ unsigned short sK[2][4096];     // [parity][64 k][64 d] swizzled
  __shared__ unsigned short sVt[2][4096];    // [parity][64 d][64 k] swizzled

  const int lin = blockIdx.x;
  const int j4 = lin >> 8;
  const int r8 = (lin >> 5) & 7;
  const int bh = lin & 31;
  const int qt = (j4 == 0) ? r8 : (j4 == 1) ? 15 - r8 : (j4 == 2) ? 16 + r8 : 31 - r8;

  const int b = bh >> 4, h = bh & 15;
  const int tid = threadIdx.x;
  const int wid = tid >> 6, lane = tid & 63;
  const int i_q = wid >> 1, jp = wid & 1;    // q-half, k-parity
  const int l31 = lane & 31, hi = lane >> 5;
  const int rowb = b * S_;

  const unsigned short* kbase = qk + (size_t)rowb * QKLD + h * 128 + 64;
  const unsigned short* vbase = vT + (size_t)bh * 64 * S_;

  const int T = qt + 1;
  const int NS = (T + 1) >> 1;
  const int qrow = qt * 64 + i_q * 32 + l31;

  // staging rows: thread covers chunks c = tid, tid+256 of each 8KB tile
  const int srow0 = tid >> 3, scol = (tid & 7) * 8;      // rows 0..31 / 32..63
  u16x8 kA[2], vA[2], kB[2], vB[2];

  auto issueA = [&](int t) {
#pragma unroll
    for (int w = 0; w < 2; w++) {
      int row = srow0 + 32 * w;
      kA[w] = *reinterpret_cast<const u16x8*>(kbase + (size_t)(t * 64 + row) * QKLD + scol);
      vA[w] = *reinterpret_cast<const u16x8*>(vbase + (size_t)row * S_ + t * 64 + scol);
    }
  };
  auto issueB = [&](int t) {
#pragma unroll
    for (int w = 0; w < 2; w++) {
      int row = srow0 + 32 * w;
      kB[w] = *reinterpret_cast<const u16x8*>(kbase + (size_t)(t * 64 + row) * QKLD + scol);
      vB[w] = *reinterpret_cast<const u16x8*>(vbase + (size_t)row * S_ + t * 64 + scol);
    }
  };
  auto writeA = [&]() {
#pragma unroll
    for (int w = 0; w < 2; w++) {
      int row = srow0 + 32 * w;
      *reinterpret_cast<u16x8*>(ldsp((unsigned short*)sK[0], swz(row, scol))) = kA[w];
      *reinterpret_cast<u16x8*>(ldsp((unsigned short*)sVt[0], swz(row, scol))) = vA[w];
    }
  };
  auto writeB = [&]() {
#pragma unroll
    for (int w = 0; w < 2; w++) {
      int row = srow0 + 32 * w;
      *reinterpret_cast<u16x8*>(ldsp((unsigned short*)sK[1], swz(row, scol))) = kB[w];
      *reinterpret_cast<u16x8*>(ldsp((unsigned short*)sVt[1], swz(row, scol))) = vB[w];
    }
  };

  short8 qf[4];
#pragma unroll
  for (int st = 0; st < 4; st++)
    qf[st] = *reinterpret_cast<const short8*>(
        qk + (size_t)(rowb + qrow) * QKLD + h * 128 + st * 16 + hi * 8);

  float m_s = -1e30f, l_s = 0.f;
  f32x16 o0, o1;
#pragma unroll
  for (int r = 0; r < 16; r++) { o0[r] = 0.f; o1[r] = 0.f; }

  issueA(0);
  if (T > 1) issueB(1);
  writeA();
  if (T > 1) writeB();
  __syncthreads();

  for (int ss = 0; ss < NS; ss++) {
    const int tA = 2 * ss + 2, tB = 2 * ss + 3;
    if (tA < T) issueA(tA);
    if (tB < T) issueB(tB);

    const int t = 2 * ss + jp;
    if (t < T) {
      const bool diag = (t == T - 1);
      f32x16 s0, s1;
      __builtin_amdgcn_s_setprio(1);
      {
        f32x16 a;
#pragma unroll
        for (int r = 0; r < 16; r++) a[r] = 0.f;
#pragma unroll
        for (int stp = 0; stp < 4; stp++) {
          short8 kf = *reinterpret_cast<const short8*>(
              ldsp((unsigned short*)sK[jp], swz(l31, stp * 16 + hi * 8)));
          a = __builtin_amdgcn_mfma_f32_32x32x16_bf16(kf, qf[stp], a, 0, 0, 0);
        }
        s0 = a;
      }
      if (!(diag && i_q == 0)) {
        f32x16 a;
#pragma unroll
        for (int r = 0; r < 16; r++) a[r] = 0.f;
#pragma unroll
        for (int stp = 0; stp < 4; stp++) {
          short8 kf = *reinterpret_cast<const short8*>(
              ldsp((unsigned short*)sK[jp], swz(32 + l31, stp * 16 + hi * 8)));
          a = __builtin_amdgcn_mfma_f32_32x32x16_bf16(kf, qf[stp], a, 0, 0, 0);
        }
        s1 = a;
      } else {
#pragma unroll
        for (int r = 0; r < 16; r++) s1[r] = -1e30f;
      }
      __builtin_amdgcn_s_setprio(0);

      if (diag) {
        const int kb0 = t * 64;
        if (i_q == 0) {
#pragma unroll
          for (int r = 0; r < 16; r++) {
            int kg = kb0 + (r & 3) + 8 * (r >> 2) + 4 * hi;
            if (kg > qrow) s0[r] = -1e30f;
          }
        } else {
#pragma unroll
          for (int r = 0; r < 16; r++) {
            int kg = kb0 + 32 + (r & 3) + 8 * (r >> 2) + 4 * hi;
            if (kg > qrow) s1[r] = -1e30f;
          }
        }
      }

      float mx = s0[0];
#pragma unroll
      for (int r = 1; r < 16; r++) mx = fmaxf(mx, s0[r]);
#pragma unroll
      for (int r = 0; r < 16; r++) mx = fmaxf(mx, s1[r]);
      mx = fmaxf(mx, __shfl_xor(mx, 32));

      if (!__all(mx <= m_s)) {          // defer-max
        float mnew = fmaxf(m_s, mx);
        float scl = fast_exp2((m_s - mnew) * C_SCALE);
        m_s = mnew;
        l_s *= scl;
#pragma unroll
        for (int r = 0; r < 16; r++) { o0[r] *= scl; o1[r] *= scl; }
      }

      const float mC = m_s * C_SCALE;
      float ps = 0.f;
#pragma unroll
      for (int r = 0; r < 16; r++) {
        s0[r] = fast_exp2(fmaf(s0[r], C_SCALE, -mC));
        ps += s0[r];
      }
#pragma unroll
      for (int r = 0; r < 16; r++) {
        s1[r] = fast_exp2(fmaf(s1[r], C_SCALE, -mC));
        ps += s1[r];
      }
      ps += __shfl_xor(ps, 32);
      l_s += ps;

      short8 pf[4];
      pf[0] = mkfrag(s0[0], s0[1], s0[2], s0[3], s0[4], s0[5], s0[6], s0[7]);
      pf[1] = mkfrag(s0[8], s0[9], s0[10], s0[11], s0[12], s0[13], s0[14], s0[15]);
      pf[2] = mkfrag(s1[0], s1[1], s1[2], s1[3], s1[4], s1[5], s1[6], s1[7]);
      pf[3] = mkfrag(s1[8], s1[9], s1[10], s1[11], s1[12], s1[13], s1[14], s1[15]);

      __builtin_amdgcn_s_setprio(1);
#pragma unroll
      for (int ks = 0; ks < 4; ks++) {
        short8 vf0 = *reinterpret_cast<const short8*>(
            ldsp((unsigned short*)sVt[jp], swz(l31, ks * 16 + hi * 8)));
        o0 = __builtin_amdgcn_mfma_f32_32x32x16_bf16(vf0, pf[ks], o0, 0, 0, 0);
        short8 vf1 = *reinterpret_cast<const short8*>(
            ldsp((unsigned short*)sVt[jp], swz(32 + l31, ks * 16 + hi * 8)));
        o1 = __builtin_amdgcn_mfma_f32_32x32x16_bf16(vf1, pf[ks], o1, 0, 0, 0);
      }
      __builtin_amdgcn_s_setprio(0);
    }

    __syncthreads();                    // everyone done reading buffers
    if (tA < T) writeA();
    if (tB < T) writeB();
    __syncthreads();                    // writes visible
  }

  // ---- merge k-parity partials (parity-1 -> LDS, parity-0 combines + stores) ----
  float* F = (float*)sK;               // 4096 floats: [i_q][32 q][64 d] (XOR-spread)
  float* M = (float*)sVt;              // m at [i_q*32+l31], l at [64 + i_q*32+l31]
  const int dk = (l31 & 7) << 3;
  if (jp == 1) {
#pragma unroll
    for (int rg = 0; rg < 4; rg++) {
      int d0 = rg * 8 + hi * 4;
      f32x4 c0, c1;
#pragma unroll
      for (int e = 0; e < 4; e++) { c0[e] = o0[rg * 4 + e]; c1[e] = o1[rg * 4 + e]; }
      *reinterpret_cast<f32x4*>(&F[i_q * 2048 + l31 * 64 + (d0 ^ dk)]) = c0;
      *reinterpret_cast<f32x4*>(&F[i_q * 2048 + l31 * 64 + ((d0 + 32) ^ dk)]) = c1;
    }
    M[i_q * 32 + l31] = m_s;           // hi=0/1 write identical values
    M[64 + i_q * 32 + l31] = l_s;
  }
  __syncthreads();
  if (jp == 0) {
    float m1 = M[i_q * 32 + l31];
    float l1 = M[64 + i_q * 32 + l31];
    float mm = fmaxf(m_s, m1);
    float a0 = fast_exp2((m_s - mm) * C_SCALE);
    float a1 = fast_exp2((m1 - mm) * C_SCALE);
    float inv = 1.f / (l_s * a0 + l1 * a1);
    float* op = &out[(size_t)(rowb + qrow) * D_ + h * 64];
#pragma unroll
    for (int rg = 0; rg < 4; rg++) {
      int d0 = rg * 8 + hi * 4;
      f32x4 c0 = *reinterpret_cast<const f32x4*>(&F[i_q * 2048 + l31 * 64 + (d0 ^ dk)]);
      f32x4 c1 = *reinterpret_cast<const f32x4*>(&F[i_q * 2048 + l31 * 64 + ((d0 + 32) ^ dk)]);
      f32x4 v0, v1;
#pragma unroll
      for (int e = 0; e < 4; e++) {
        v0[e] = (o0[rg * 4 + e] * a0 + c0[e] * a1) * inv;
        v1[e] = (o1[rg * 4 + e] * a0 + c1[e] * a1) * inv;
      }
      *reinterpret_cast<f32x4*>(&op[d0]) = v0;
      *reinterpret_cast<f32x4*>(&op[32 + d0]) = v1;
    }
  }
}

extern "C" void kernel_launch(void* const* d_in, const int* in_sizes, int n_in,
                              void* d_out, int out_size, void* d_ws, size_t ws_size,
                              hipStream_t stream) {
  const float* x    = (const float*)d_in[0];
  const float* W    = (const float*)d_in[1];
  const float* bias = (const float*)d_in[2];
  float* out = (float*)d_out;
  char* ws = (char*)d_ws;
  unsigned short* xb  = (unsigned short*)(ws);                    // 8 MB
  unsigned short* wt  = (unsigned short*)(ws + (8u << 20));       // 6 MB
  unsigned short* qk  = (unsigned short*)(ws + (14u << 20));      // 16 MB
  unsigned short* vTb = (unsigned short*)(ws + (30u << 20));      // 8 MB

  conv_x_kernel<<<4096, 256, 0, stream>>>(x, xb);
  transpose_w_kernel<<<dim3(48, 16), 256, 0, stream>>>(W, wt);
  qkv_gemm_kernel<<<dim3(24, 32), 256, 0, stream>>>(xb, wt, bias, qk, vTb);
  attn_kernel<<<1024, 256, 0, stream>>>(qk, vTb, out);
}